// Round 1
// 11477.818 us; speedup vs baseline: 1.2981x; 1.2981x over previous
//
#include <hip/hip_runtime.h>
#include <hip/hip_bf16.h>

typedef _Float16 f16;
typedef _Float16 f16x8 __attribute__((ext_vector_type(8)));
typedef float f32x4 __attribute__((ext_vector_type(4)));

#define SN 2048
#define IN_ 128
#define TCH 32
#define WUP 96
#define RR 32
#define HPAD 280

#define WB0_SZ (384 * 1024)
#define WB1_SZ (512 * 1024)
#define WBO_SZ (256 * 128)
#define BIAS_OFF_B ((WB0_SZ + WB1_SZ + WBO_SZ) * 2)

struct PrepArgs {
  const float* W[8];   // ff1_0, ff2_0, ta_0, tb_0, ff1_1, ff2_1, ta_1, tb_1
  const float* b[8];
  const float* Wout;
  const float* bout;
};

// Pack f32 weights into per-(frag,lane) f16x8 groups.
// k-map (identical for A and B fragments -> permutation-safe):
//   element e of lane l in k-tile kt covers k = kt*32 + (l>>4)*8 + e
//   col n = nt*16 + (l&15)
__global__ void prep_kernel(PrepArgs p, f16* wbase, float* bbase) {
  int g = blockIdx.x * blockDim.x + threadIdx.x;
  const int NF0 = 12 * 64;
  const int NF1 = 16 * 64;
  const int NFO = 8 * 8;
  const int E0 = NF0 * 64, E1 = E0 + NF1 * 64, E2 = E1 + NFO * 64;
  if (g < E0) {
    int f = g >> 6, lane = g & 63;
    int kt = f >> 6, nt = f & 63;
    int k = kt * 32 + ((lane >> 4) << 3);
    int n = nt * 16 + (lane & 15);
    const float* W = p.W[n >> 8];    // layer0 weight [384][256]
    int j = n & 255;
    f16x8 v;
#pragma unroll
    for (int e = 0; e < 8; ++e) v[e] = (f16)W[(k + e) * 256 + j];
    *(f16x8*)(wbase + (size_t)g * 8) = v;
  } else if (g < E1) {
    int g1 = g - E0;
    int f = g1 >> 6, lane = g1 & 63;
    int kt = f >> 6, nt = f & 63;
    int k = kt * 32 + ((lane >> 4) << 3);
    int n = nt * 16 + (lane & 15);
    const float* W = p.W[4 + (n >> 8)];  // layer1 weight [512][256]
    int j = n & 255;
    f16x8 v;
#pragma unroll
    for (int e = 0; e < 8; ++e) v[e] = (f16)W[(k + e) * 256 + j];
    *(f16x8*)(wbase + (size_t)WB0_SZ + (size_t)g1 * 8) = v;
  } else if (g < E2) {
    int g2 = g - E1;
    int f = g2 >> 6, lane = g2 & 63;
    int kt = f >> 3, nt = f & 7;
    int k = kt * 32 + ((lane >> 4) << 3);
    int n = nt * 16 + (lane & 15);
    f16x8 v;
#pragma unroll
    for (int e = 0; e < 8; ++e) v[e] = (f16)p.Wout[(k + e) * 128 + n];
    *(f16x8*)(wbase + (size_t)(WB0_SZ + WB1_SZ) + (size_t)g2 * 8) = v;
  } else {
    int g3 = g - E2;
    if (g3 < 1024) {
      bbase[g3] = p.b[g3 >> 8][g3 & 255];
    } else if (g3 < 2048) {
      int q = g3 - 1024;
      bbase[1024 + q] = p.b[4 + (q >> 8)][q & 255];
    } else if (g3 < 2176) {
      bbase[2048 + (g3 - 2048)] = p.bout[g3 - 2048];
    }
  }
}

__device__ __forceinline__ float fast_tanh(float v) {
  float e = __expf(2.f * v);
  return 1.f - 2.f / (e + 1.f);
}
__device__ __forceinline__ float fast_sigmoid(float v) {
  return 1.f / (1.f + __expf(-v));
}

// 256 blocks = 64 time-chunks (TCH=32, WUP=96) x 4 row-groups of 32 rows.
// Wave w owns h-cols [32w,32w+32): gate n-tiles {g*16 + 2w + s} for g=0..3,
// s=0..1 -> all four gates of a given (row,col) sit in the SAME lane ->
// elementwise fully in registers, no gate round-trip through LDS.
__global__ __launch_bounds__(512, 2)
void scan_kernel(const float* __restrict__ x, const float* __restrict__ dtp,
                 const f16* __restrict__ wb0, const f16* __restrict__ wb1,
                 const f16* __restrict__ wbO, const float* __restrict__ bb,
                 float* __restrict__ out) {   // *** d_out is FLOAT32 ***
  __shared__ __align__(16) f16 xA[RR][136];
  __shared__ __align__(16) f16 h0s[2][RR][HPAD];   // double-buffered states
  __shared__ __align__(16) f16 h1s[2][RR][HPAD];
  __shared__ float bs0[1024];
  __shared__ float bs1[1024];
  __shared__ float bsO[128];
  __shared__ float dts[RR];

  const int tid = threadIdx.x;
  const int lane = tid & 63;
  const int w = tid >> 6;
  const int c = blockIdx.x >> 2;          // time chunk 0..63
  const int r0 = (blockIdx.x & 3) * RR;   // batch-row base

  for (int i = tid; i < 1024; i += 512) { bs0[i] = bb[i]; bs1[i] = bb[1024 + i]; }
  if (tid < 128) bsO[tid] = bb[2048 + tid];
  for (int i = tid; i < 2 * RR * HPAD; i += 512) {
    (&h0s[0][0][0])[i] = (f16)0.f;
    (&h1s[0][0][0])[i] = (f16)0.f;
  }

  int tb = c * TCH - WUP;
  if (tb < 0) tb = 0;
  const int te = (c + 1) * TCH;
  const int tw = c * TCH;

  const int mrow = lane & 15;
  const int kgrp = (lane >> 4) * 8;
  const int rbase = (lane >> 4) * 4;

  // Out-projection weights live in registers for the whole scan (zero
  // global loads in the out phase). Wave w -> out n-tile w.
  f16x8 wor[8];
#pragma unroll
  for (int kt = 0; kt < 8; ++kt)
    wor[kt] = *((const f16x8*)wbO + (size_t)(kt * 8 + w) * 64 + lane);

  // x/dt prefetch: thread covers 8 cols of one row
  const int xi = tid >> 4;
  const int xk = (tid & 15) * 8;
  float4 xr0 = *(const float4*)(x + ((size_t)(r0 + xi) * SN + tb) * IN_ + xk);
  float4 xr1 = *(const float4*)(x + ((size_t)(r0 + xi) * SN + tb) * IN_ + xk + 4);
  float dtr = 0.f;
  if (tid < RR) dtr = dtp[(size_t)(r0 + tid) * SN + tb];

  int rp = 0;  // read-parity of h buffers
  for (int t = tb; t < te; ++t) {
    { f16x8 xv = { (f16)xr0.x, (f16)xr0.y, (f16)xr0.z, (f16)xr0.w,
                   (f16)xr1.x, (f16)xr1.y, (f16)xr1.z, (f16)xr1.w };
      *(f16x8*)&xA[xi][xk] = xv; }
    if (tid < RR) dts[tid] = dtr;
    __syncthreads();                                   // B0: xA/dts visible
    if (t + 1 < te) {
      xr0 = *(const float4*)(x + ((size_t)(r0 + xi) * SN + (t + 1)) * IN_ + xk);
      xr1 = *(const float4*)(x + ((size_t)(r0 + xi) * SN + (t + 1)) * IN_ + xk + 4);
      if (tid < RR) dtr = dtp[(size_t)(r0 + tid) * SN + (t + 1)];
    }
    const int wp = rp ^ 1;

    // ---- layer 0 gates: [32 x 1024] = [x(32x128) | h0(32x256)] @ W0cat ----
    {
      f32x4 acc[4][2][2];   // [gate][subtile][mtile]
#pragma unroll
      for (int g = 0; g < 4; ++g)
#pragma unroll
        for (int s = 0; s < 2; ++s) {
          float bv = bs0[(g * 16 + 2 * w + s) * 16 + mrow];
          acc[g][s][0] = (f32x4){bv, bv, bv, bv};
          acc[g][s][1] = (f32x4){bv, bv, bv, bv};
        }
#pragma unroll
      for (int kt = 0; kt < 12; ++kt) {
        f16x8 a0, a1;
        if (kt < 4) {
          a0 = *(const f16x8*)&xA[mrow][kt * 32 + kgrp];
          a1 = *(const f16x8*)&xA[16 + mrow][kt * 32 + kgrp];
        } else {
          a0 = *(const f16x8*)&h0s[rp][mrow][(kt - 4) * 32 + kgrp];
          a1 = *(const f16x8*)&h0s[rp][16 + mrow][(kt - 4) * 32 + kgrp];
        }
        const f16x8* bp = (const f16x8*)wb0 + ((size_t)(kt * 64) * 64 + lane);
#pragma unroll
        for (int g = 0; g < 4; ++g)
#pragma unroll
          for (int s = 0; s < 2; ++s) {
            f16x8 b = bp[(g * 16 + 2 * w + s) * 64];
            acc[g][s][0] = __builtin_amdgcn_mfma_f32_16x16x32_f16(a0, b, acc[g][s][0], 0, 0, 0);
            acc[g][s][1] = __builtin_amdgcn_mfma_f32_16x16x32_f16(a1, b, acc[g][s][1], 0, 0, 0);
          }
      }
      // elementwise in registers -> h0 new buffer (disjoint from h0[rp])
#pragma unroll
      for (int s = 0; s < 2; ++s)
#pragma unroll
        for (int mt = 0; mt < 2; ++mt)
#pragma unroll
          for (int ri = 0; ri < 4; ++ri) {
            int row = mt * 16 + rbase + ri;
            float d = dts[row];
            float f1 = fast_tanh(acc[0][s][mt][ri]);
            float f2 = fast_tanh(acc[1][s][mt][ri]);
            float sg = fast_sigmoid(acc[2][s][mt][ri] * d + acc[3][s][mt][ri]);
            h0s[wp][row][w * 32 + s * 16 + mrow] = (f16)(f1 + sg * (f2 - f1));
          }
    }
    __syncthreads();                                   // B1: new h0 visible

    // ---- layer 1 gates: [32 x 1024] = [h0_new | h1_old] @ W1cat ----
    {
      f32x4 acc[4][2][2];
#pragma unroll
      for (int g = 0; g < 4; ++g)
#pragma unroll
        for (int s = 0; s < 2; ++s) {
          float bv = bs1[(g * 16 + 2 * w + s) * 16 + mrow];
          acc[g][s][0] = (f32x4){bv, bv, bv, bv};
          acc[g][s][1] = (f32x4){bv, bv, bv, bv};
        }
#pragma unroll
      for (int kt = 0; kt < 16; ++kt) {
        f16x8 a0, a1;
        if (kt < 8) {
          a0 = *(const f16x8*)&h0s[wp][mrow][kt * 32 + kgrp];
          a1 = *(const f16x8*)&h0s[wp][16 + mrow][kt * 32 + kgrp];
        } else {
          a0 = *(const f16x8*)&h1s[rp][mrow][(kt - 8) * 32 + kgrp];
          a1 = *(const f16x8*)&h1s[rp][16 + mrow][(kt - 8) * 32 + kgrp];
        }
        const f16x8* bp = (const f16x8*)wb1 + ((size_t)(kt * 64) * 64 + lane);
#pragma unroll
        for (int g = 0; g < 4; ++g)
#pragma unroll
          for (int s = 0; s < 2; ++s) {
            f16x8 b = bp[(g * 16 + 2 * w + s) * 64];
            acc[g][s][0] = __builtin_amdgcn_mfma_f32_16x16x32_f16(a0, b, acc[g][s][0], 0, 0, 0);
            acc[g][s][1] = __builtin_amdgcn_mfma_f32_16x16x32_f16(a1, b, acc[g][s][1], 0, 0, 0);
          }
      }
#pragma unroll
      for (int s = 0; s < 2; ++s)
#pragma unroll
        for (int mt = 0; mt < 2; ++mt)
#pragma unroll
          for (int ri = 0; ri < 4; ++ri) {
            int row = mt * 16 + rbase + ri;
            float d = dts[row];
            float f1 = fast_tanh(acc[0][s][mt][ri]);
            float f2 = fast_tanh(acc[1][s][mt][ri]);
            float sg = fast_sigmoid(acc[2][s][mt][ri] * d + acc[3][s][mt][ri]);
            h1s[wp][row][w * 32 + s * 16 + mrow] = (f16)(f1 + sg * (f2 - f1));
          }
    }
    __syncthreads();                                   // B2: new h1 visible

    // ---- y = h1 @ Wout + bout (weights in regs; skipped during warmup) ----
    if (t >= tw) {
      float bv = bsO[w * 16 + mrow];
      f32x4 ao0 = (f32x4){bv, bv, bv, bv};
      f32x4 ao1 = (f32x4){bv, bv, bv, bv};
#pragma unroll
      for (int kt = 0; kt < 8; ++kt) {
        f16x8 a0 = *(const f16x8*)&h1s[wp][mrow][kt * 32 + kgrp];
        f16x8 a1 = *(const f16x8*)&h1s[wp][16 + mrow][kt * 32 + kgrp];
        ao0 = __builtin_amdgcn_mfma_f32_16x16x32_f16(a0, wor[kt], ao0, 0, 0, 0);
        ao1 = __builtin_amdgcn_mfma_f32_16x16x32_f16(a1, wor[kt], ao1, 0, 0, 0);
      }
#pragma unroll
      for (int ri = 0; ri < 4; ++ri) {
        int r = rbase + ri;
        out[((size_t)(r0 + r) * SN + t) * 128 + w * 16 + mrow] = ao0[ri];
        out[((size_t)(r0 + 16 + r) * SN + t) * 128 + w * 16 + mrow] = ao1[ri];
      }
    }
    rp ^= 1;
    // next-iter xA/dts stores race only with the out phase (disjoint LDS);
    // B0 at the top of the loop orders everything else.
  }
}

extern "C" void kernel_launch(void* const* d_in, const int* in_sizes, int n_in,
                              void* d_out, int out_size, void* d_ws, size_t ws_size,
                              hipStream_t stream) {
  PrepArgs p;
  for (int i = 0; i < 8; ++i) {
    p.W[i] = (const float*)d_in[2 + 2 * i];
    p.b[i] = (const float*)d_in[3 + 2 * i];
  }
  p.Wout = (const float*)d_in[18];
  p.bout = (const float*)d_in[19];
  const float* x  = (const float*)d_in[0];
  const float* dt = (const float*)d_in[1];

  f16* wbase = (f16*)d_ws;
  float* bbase = (float*)((char*)d_ws + BIAS_OFF_B);

  const int prep_threads = (12 * 64 + 16 * 64 + 8 * 8) * 64 + 2176;
  int prep_blocks = (prep_threads + 255) / 256;
  prep_kernel<<<prep_blocks, 256, 0, stream>>>(p, wbase, bbase);

  const f16* wb0 = wbase;
  const f16* wb1 = wbase + WB0_SZ;
  const f16* wbO = wbase + WB0_SZ + WB1_SZ;

  scan_kernel<<<256, 512, 0, stream>>>(x, dt, wb0, wb1, wbO,
                                       (const float*)bbase, (float*)d_out);
}